// Round 2
// baseline (26.892 us; speedup 1.0000x reference)
//
#include <hip/hip_runtime.h>
#include <stdint.h>

// ACOLayer: reproduce JAX's sampling exactly.
//   u = jax.random.uniform(key(42), (32, 4096, 16), f32)
//   idx[b,i,a] = searchsorted(cdf_row_i, u[b,i,a]) clamped; -1 where a >= x[b,i]
//
// RNG: jax_threefry_partitionable=True (default since jax 0.4.30):
//   bits[i] = o0 ^ o1 where (o0,o1) = threefry2x32(key=(0,42), counter=(i>>32, i&0xffffffff))
//   For i < 2^21 the hi word is 0, so counter = (0, i).
// u = bitcast((bits>>9)|0x3f800000) - 1.0f

#define N_IN   4096
#define N_OUT  4096
#define BS     32
#define MAX_A  16
#define THREADS 256
#define HALF   1048576u  /* 16 * N_IN * MAX_A */

// padded LDS index: break power-of-2 bank pattern in the binary search
__device__ __forceinline__ int padi(int j) { return j + (j >> 5); }

__device__ __forceinline__ uint32_t rotl32(uint32_t x, uint32_t r) {
    return (x << r) | (x >> (32u - r));
}

// Threefry-2x32, 20 rounds, key (0, 42) — matches jax.random.key(42)
__device__ __forceinline__ void threefry2x32_42(uint32_t x0, uint32_t x1,
                                                uint32_t& o0, uint32_t& o1) {
    const uint32_t k0 = 0u, k1 = 42u;
    const uint32_t k2 = k0 ^ k1 ^ 0x1BD11BDAu;
    x0 += k0; x1 += k1;
#define TF_R(r) { x0 += x1; x1 = rotl32(x1, (r)); x1 ^= x0; }
    TF_R(13) TF_R(15) TF_R(26) TF_R(6)
    x0 += k1; x1 += k2 + 1u;
    TF_R(17) TF_R(29) TF_R(16) TF_R(24)
    x0 += k2; x1 += k0 + 2u;
    TF_R(13) TF_R(15) TF_R(26) TF_R(6)
    x0 += k0; x1 += k1 + 3u;
    TF_R(17) TF_R(29) TF_R(16) TF_R(24)
    x0 += k1; x1 += k2 + 4u;
    TF_R(13) TF_R(15) TF_R(26) TF_R(6)
    x0 += k2; x1 += k0 + 5u;
#undef TF_R
    o0 = x0; o1 = x1;
}

// JAX f32 uniform from 32 random bits
__device__ __forceinline__ float bits_to_uniform(uint32_t b) {
    uint32_t f = (b >> 9) | 0x3f800000u;
    float r;
    __builtin_memcpy(&r, &f, 4);
    return r - 1.0f;
}

__device__ __forceinline__ int lower_bound_cdf(const float* cdf, float u) {
    int lo = 0, hi = N_OUT;
    #pragma unroll
    for (int it = 0; it < 12; ++it) {   // 4096 = 2^12 -> exactly 12 halvings
        int mid = (lo + hi) >> 1;
        if (cdf[padi(mid)] < u) lo = mid + 1; else hi = mid;
    }
    return lo < N_OUT ? lo : N_OUT - 1; // jnp.minimum(idx, n_out-1)
}

__global__ __launch_bounds__(THREADS)
void aco_sample_kernel(const int* __restrict__ x,
                       const float* __restrict__ w,
                       int* __restrict__ out) {
    __shared__ float cdf[N_OUT + (N_OUT >> 5)];  // padded
    __shared__ float tsum[THREADS];
    __shared__ int   xc[BS];

    const int row = blockIdx.x;
    const int t   = threadIdx.x;

    // stage weight row (coalesced)
    for (int j = t; j < N_OUT; j += THREADS)
        cdf[padi(j)] = w[(size_t)row * N_OUT + j];
    if (t < BS) xc[t] = x[t * N_IN + row];
    __syncthreads();

    // local inclusive scan of 16 contiguous elements per thread
    float loc[16];
    float s = 0.f;
    const int base = t * 16;
    #pragma unroll
    for (int k = 0; k < 16; ++k) { s += cdf[padi(base + k)]; loc[k] = s; }
    tsum[t] = s;
    __syncthreads();

    // Hillis-Steele inclusive scan over 256 per-thread totals
    for (int off = 1; off < THREADS; off <<= 1) {
        float v   = tsum[t];
        float add = (t >= off) ? tsum[t - off] : 0.f;
        __syncthreads();
        tsum[t] = v + add;
        __syncthreads();
    }
    const float total   = tsum[THREADS - 1];
    const float inv_tot = 1.0f / total;
    const float prefix  = (t > 0) ? tsum[t - 1] : 0.f;

    // write normalized CDF back (each thread owns its own chunk; no hazard)
    #pragma unroll
    for (int k = 0; k < 16; ++k)
        cdf[padi(base + k)] = (prefix + loc[k]) * inv_tot;
    __syncthreads();

    // two draws per thread: (b, row, a) and (b+16, row, a)
    const int b = t >> 4;   // 0..15
    const int a = t & 15;
    const uint32_t j0 = (uint32_t)(b * (N_IN * MAX_A) + row * MAX_A + a);
    const uint32_t j1 = j0 + HALF;

    uint32_t o0, o1, p0, p1;
    threefry2x32_42(0u, j0, o0, o1);   // partitionable: counter = (0, flat_idx)
    threefry2x32_42(0u, j1, p0, p1);
    const float u0 = bits_to_uniform(o0 ^ o1);   // xor-fold of the two outputs
    const float u1 = bits_to_uniform(p0 ^ p1);

    const int idx0 = lower_bound_cdf(cdf, u0);
    const int idx1 = lower_bound_cdf(cdf, u1);

    out[j0] = (a < xc[b])      ? idx0 : -1;
    out[j1] = (a < xc[b + 16]) ? idx1 : -1;
}

extern "C" void kernel_launch(void* const* d_in, const int* in_sizes, int n_in,
                              void* d_out, int out_size, void* d_ws, size_t ws_size,
                              hipStream_t stream) {
    // Select inputs BY SIZE, robust to either ordering:
    //   x: 32*4096 = 131072 int32;  weights: 4096*4096 = 16777216 f32
    const void* p0 = d_in[0];
    const void* p1 = d_in[1];
    const int*   x;
    const float* w;
    if (in_sizes[0] == BS * N_IN) { x = (const int*)p0; w = (const float*)p1; }
    else                          { x = (const int*)p1; w = (const float*)p0; }
    int* out = (int*)d_out;
    aco_sample_kernel<<<N_IN, THREADS, 0, stream>>>(x, w, out);
}

// Round 3
// 21.349 us; speedup vs baseline: 1.2596x; 1.2596x over previous
//
#include <hip/hip_runtime.h>
#include <stdint.h>

// ACOLayer: reproduce JAX's sampling exactly.
//   u = jax.random.uniform(key(42), (32, 4096, 16), f32)
//   idx[b,i,a] = searchsorted(cdf_row_i, u[b,i,a]) clamped; -1 where a >= x[b,i]
// RNG: jax_threefry_partitionable=True stream:
//   bits[i] = o0 ^ o1, (o0,o1) = threefry2x32(key=(0,42), counter=(0, i))  [i < 2^32]
//   u = bitcast((bits>>9)|0x3f800000) - 1.0f
// Search: unnormalized cumsum S, target u*S_total (== normalized search ±1 ulp-index).

#define N_IN   4096
#define N_OUT  4096
#define BS     32
#define MAX_A  16
#define THREADS 256
#define HALF   1048576u  /* 16 * N_IN * MAX_A */

// pad +4 floats per 64: breaks power-of-2 bank strides, keeps every 16-aligned
// chunk contiguous (so ds_write_b128 / aligned float4 writes stay legal)
__device__ __forceinline__ int padi(int j) { return j + ((j >> 6) << 2); }

__device__ __forceinline__ uint32_t rotl32(uint32_t x, uint32_t r) {
    return (x << r) | (x >> (32u - r));
}

// Threefry-2x32, 20 rounds, key (0, 42) — jax.random.key(42)
__device__ __forceinline__ void threefry2x32_42(uint32_t x0, uint32_t x1,
                                                uint32_t& o0, uint32_t& o1) {
    const uint32_t k0 = 0u, k1 = 42u;
    const uint32_t k2 = k0 ^ k1 ^ 0x1BD11BDAu;
    x0 += k0; x1 += k1;
#define TF_R(r) { x0 += x1; x1 = rotl32(x1, (r)); x1 ^= x0; }
    TF_R(13) TF_R(15) TF_R(26) TF_R(6)
    x0 += k1; x1 += k2 + 1u;
    TF_R(17) TF_R(29) TF_R(16) TF_R(24)
    x0 += k2; x1 += k0 + 2u;
    TF_R(13) TF_R(15) TF_R(26) TF_R(6)
    x0 += k0; x1 += k1 + 3u;
    TF_R(17) TF_R(29) TF_R(16) TF_R(24)
    x0 += k1; x1 += k2 + 4u;
    TF_R(13) TF_R(15) TF_R(26) TF_R(6)
    x0 += k2; x1 += k0 + 5u;
#undef TF_R
    o0 = x0; o1 = x1;
}

__device__ __forceinline__ float bits_to_uniform(uint32_t b) {
    uint32_t f = (b >> 9) | 0x3f800000u;
    float r;
    __builtin_memcpy(&r, &f, 4);
    return r - 1.0f;
}

__device__ __forceinline__ int lower_bound_cdf(const float* cdf, float tval) {
    int lo = 0, hi = N_OUT;
    #pragma unroll
    for (int it = 0; it < 12; ++it) {   // 4096 = 2^12
        int mid = (lo + hi) >> 1;
        if (cdf[padi(mid)] < tval) lo = mid + 1; else hi = mid;
    }
    return lo < N_OUT ? lo : N_OUT - 1;
}

__global__ __launch_bounds__(THREADS)
void aco_sample_kernel(const int* __restrict__ x,
                       const float* __restrict__ w,
                       int* __restrict__ out) {
    __shared__ float cdf[N_OUT + (N_OUT >> 4)];  // +4 per 64
    __shared__ float wsum[4];
    __shared__ int   xc[BS];

    const int row  = blockIdx.x;
    const int t    = threadIdx.x;
    const int lane = t & 63;
    const int wid  = t >> 6;

    // ---- stage 16 weights directly into registers (4x float4) ----
    const float4* wrow = (const float4*)(w + (size_t)row * N_OUT);
    float4 v0 = wrow[t * 4 + 0];
    float4 v1 = wrow[t * 4 + 1];
    float4 v2 = wrow[t * 4 + 2];
    float4 v3 = wrow[t * 4 + 3];

    if (t < BS) xc[t] = x[t * N_IN + row];

    // ---- local inclusive scan of 16 values in registers ----
    float loc[16];
    {
        float s = 0.f;
        s += v0.x; loc[0]  = s;  s += v0.y; loc[1]  = s;
        s += v0.z; loc[2]  = s;  s += v0.w; loc[3]  = s;
        s += v1.x; loc[4]  = s;  s += v1.y; loc[5]  = s;
        s += v1.z; loc[6]  = s;  s += v1.w; loc[7]  = s;
        s += v2.x; loc[8]  = s;  s += v2.y; loc[9]  = s;
        s += v2.z; loc[10] = s;  s += v2.w; loc[11] = s;
        s += v3.x; loc[12] = s;  s += v3.y; loc[13] = s;
        s += v3.z; loc[14] = s;  s += v3.w; loc[15] = s;
    }
    const float my_total = loc[15];

    // ---- wave-level inclusive scan of per-thread totals (register shuffles) ----
    float incl = my_total;
    #pragma unroll
    for (int d = 1; d < 64; d <<= 1) {
        float n = __shfl_up(incl, d, 64);
        if (lane >= d) incl += n;
    }
    if (lane == 63) wsum[wid] = incl;
    __syncthreads();

    // ---- block prefix + total ----
    const float4 ws = *(const float4*)wsum;
    const float total = ws.x + ws.y + ws.z + ws.w;
    float wprefix = 0.f;
    if (wid > 0) wprefix += ws.x;
    if (wid > 1) wprefix += ws.y;
    if (wid > 2) wprefix += ws.z;
    const float chunk_prefix = wprefix + incl - my_total;  // exclusive prefix of my 16

    // ---- write unnormalized cumsum to LDS (contiguous 16B chunks) ----
    float* cbase = &cdf[padi(t * 16)];
    {
        float4 a, b, c, d;
        a.x = chunk_prefix + loc[0];  a.y = chunk_prefix + loc[1];
        a.z = chunk_prefix + loc[2];  a.w = chunk_prefix + loc[3];
        b.x = chunk_prefix + loc[4];  b.y = chunk_prefix + loc[5];
        b.z = chunk_prefix + loc[6];  b.w = chunk_prefix + loc[7];
        c.x = chunk_prefix + loc[8];  c.y = chunk_prefix + loc[9];
        c.z = chunk_prefix + loc[10]; c.w = chunk_prefix + loc[11];
        d.x = chunk_prefix + loc[12]; d.y = chunk_prefix + loc[13];
        d.z = chunk_prefix + loc[14]; d.w = chunk_prefix + loc[15];
        ((float4*)cbase)[0] = a;
        ((float4*)cbase)[1] = b;
        ((float4*)cbase)[2] = c;
        ((float4*)cbase)[3] = d;
    }
    __syncthreads();

    // ---- two draws per thread: (b, row, a) and (b+16, row, a) ----
    const int b = t >> 4;   // 0..15
    const int a = t & 15;
    const uint32_t j0 = (uint32_t)(b * (N_IN * MAX_A) + row * MAX_A + a);
    const uint32_t j1 = j0 + HALF;

    uint32_t o0, o1, p0, p1;
    threefry2x32_42(0u, j0, o0, o1);
    threefry2x32_42(0u, j1, p0, p1);
    const float t0 = bits_to_uniform(o0 ^ o1) * total;
    const float t1 = bits_to_uniform(p0 ^ p1) * total;

    const int idx0 = lower_bound_cdf(cdf, t0);
    const int idx1 = lower_bound_cdf(cdf, t1);

    out[j0] = (a < xc[b])      ? idx0 : -1;
    out[j1] = (a < xc[b + 16]) ? idx1 : -1;
}

extern "C" void kernel_launch(void* const* d_in, const int* in_sizes, int n_in,
                              void* d_out, int out_size, void* d_ws, size_t ws_size,
                              hipStream_t stream) {
    // select inputs by size (robust to ordering):
    //   x: 32*4096 int32; weights: 4096*4096 f32
    const int*   x;
    const float* w;
    if (in_sizes[0] == BS * N_IN) { x = (const int*)d_in[0]; w = (const float*)d_in[1]; }
    else                          { x = (const int*)d_in[1]; w = (const float*)d_in[0]; }
    aco_sample_kernel<<<N_IN, THREADS, 0, stream>>>(x, w, (int*)d_out);
}